// Round 1
// baseline (173.796 us; speedup 1.0000x reference)
//
#include <hip/hip_runtime.h>

// SparseLayer: out[n] = mean(concat(self_h, neigh_h)) + bias
//            == ((self[n] + sum_j neigh[n*32+j]) / 33) @ W + bias
// N=50000, NEIGH=32, D_IN=D_OUT=128, all fp32.

constexpr int D       = 128;
constexpr int NEIGH   = 32;
constexpr int NPB     = 16;   // nodes per block (50000 = 16 * 3125)
constexpr int THREADS = 512;  // 8 waves; 32 lanes (float4 cols) x 16 nodes

__global__ __launch_bounds__(THREADS, 4)
void sparse_layer_fused(const float* __restrict__ self_vecs,
                        const float* __restrict__ neigh_vecs,
                        const float* __restrict__ weight,
                        const float* __restrict__ bias,
                        float* __restrict__ out)
{
    __shared__ float w_lds[D * D];        // 64 KiB: W[k][j], row-major
    __shared__ float agg_lds[NPB][D];     // 8 KiB: aggregated inputs

    // ---- stage W into LDS (coalesced float4, 8 iters/thread) ----
    {
        const float4* w4 = reinterpret_cast<const float4*>(weight);
        float4*       wl = reinterpret_cast<float4*>(w_lds);
        #pragma unroll
        for (int i = 0; i < (D * D / 4) / THREADS; ++i)
            wl[threadIdx.x + i * THREADS] = w4[threadIdx.x + i * THREADS];
    }

    const int  local = threadIdx.x >> 5;   // node within block: 0..15
    const int  c4    = threadIdx.x & 31;   // float4 column: 0..31
    const long node  = (long)blockIdx.x * NPB + local;

    // ---- phase 1: aggregate self + 32 neighbours (contiguous 16 KiB/node) ----
    const float4* s4 = reinterpret_cast<const float4*>(self_vecs);
    const float4* n4 = reinterpret_cast<const float4*>(neigh_vecs);

    float4 acc = s4[node * (D / 4) + c4];
    const float4* nrow = n4 + node * (long)NEIGH * (D / 4) + c4;
    #pragma unroll 8
    for (int r = 0; r < NEIGH; ++r) {
        float4 v = nrow[(long)r * (D / 4)];
        acc.x += v.x; acc.y += v.y; acc.z += v.z; acc.w += v.w;
    }
    constexpr float inv = 1.0f / 33.0f;
    float4 sc;
    sc.x = acc.x * inv; sc.y = acc.y * inv; sc.z = acc.z * inv; sc.w = acc.w * inv;
    reinterpret_cast<float4*>(agg_lds[local])[c4] = sc;

    __syncthreads();

    // ---- phase 2: out[node][4*c4 .. +3] = agg[node] @ W + bias ----
    float4 o = make_float4(0.f, 0.f, 0.f, 0.f);
    const float4* arow4 = reinterpret_cast<const float4*>(agg_lds[local]);
    #pragma unroll 4
    for (int k4 = 0; k4 < D / 4; ++k4) {
        float4 a  = arow4[k4];                                              // broadcast (2-way: free)
        float4 w0 = reinterpret_cast<const float4*>(w_lds + (4*k4+0) * D)[c4];
        float4 w1 = reinterpret_cast<const float4*>(w_lds + (4*k4+1) * D)[c4];
        float4 w2 = reinterpret_cast<const float4*>(w_lds + (4*k4+2) * D)[c4];
        float4 w3 = reinterpret_cast<const float4*>(w_lds + (4*k4+3) * D)[c4];
        o.x += a.x * w0.x; o.y += a.x * w0.y; o.z += a.x * w0.z; o.w += a.x * w0.w;
        o.x += a.y * w1.x; o.y += a.y * w1.y; o.z += a.y * w1.z; o.w += a.y * w1.w;
        o.x += a.z * w2.x; o.y += a.z * w2.y; o.z += a.z * w2.z; o.w += a.z * w2.w;
        o.x += a.w * w3.x; o.y += a.w * w3.y; o.z += a.w * w3.z; o.w += a.w * w3.w;
    }
    float4 b = reinterpret_cast<const float4*>(bias)[c4];
    o.x += b.x; o.y += b.y; o.z += b.z; o.w += b.w;
    reinterpret_cast<float4*>(out)[node * (D / 4) + c4] = o;
}

extern "C" void kernel_launch(void* const* d_in, const int* in_sizes, int n_in,
                              void* d_out, int out_size, void* d_ws, size_t ws_size,
                              hipStream_t stream) {
    const float* self_vecs  = (const float*)d_in[0];
    const float* neigh_vecs = (const float*)d_in[1];
    // d_in[2] = neigh_num (int scalar == 32; compile-time constant NEIGH)
    const float* weight     = (const float*)d_in[3];
    const float* bias       = (const float*)d_in[4];
    float*       out        = (float*)d_out;

    const int n_nodes = in_sizes[0] / D;   // 50000
    const int blocks  = n_nodes / NPB;     // 3125 (exact)
    hipLaunchKernelGGL(sparse_layer_fused, dim3(blocks), dim3(THREADS), 0, stream,
                       self_vecs, neigh_vecs, weight, bias, out);
}

// Round 3
// 173.362 us; speedup vs baseline: 1.0025x; 1.0025x over previous
//
#include <hip/hip_runtime.h>

// SparseLayer: out[n] = ((self[n] + sum_j neigh[n*32+j]) / 33) @ W + bias
// N=50000, NEIGH=32, D=128, fp32.
//
// Per-wave independent pipeline, no inter-phase barrier (agg rows produced and
// consumed by the same wave). Each lane computes 2 nodes per W-fragment read.

typedef float f32x4 __attribute__((ext_vector_type(4)));

constexpr int D        = 128;
constexpr int NEIGH    = 32;
constexpr int WAVES    = 8;
constexpr int THREADS  = WAVES * 64;          // 512
constexpr int NPW      = 4;                   // nodes per wave
constexpr int NPB      = WAVES * NPW;         // 32 nodes per block

__global__ __launch_bounds__(THREADS, 4)      // 4 waves/SIMD = 2 blocks/CU
void sparse_layer_fused(const float* __restrict__ self_vecs,
                        const float* __restrict__ neigh_vecs,
                        const float* __restrict__ weight,
                        const float* __restrict__ bias,
                        float* __restrict__ out, int n_nodes)
{
    __shared__ float w_lds[D * D];            // 64 KiB
    __shared__ float agg_lds[NPB][D];         // 16 KiB  (80 KiB total -> 2 blocks/CU)

    // ---- stage W into LDS (only block-wide sync in the kernel) ----
    {
        const f32x4* w4 = reinterpret_cast<const f32x4*>(weight);
        f32x4*       wl = reinterpret_cast<f32x4*>(w_lds);
        #pragma unroll
        for (int i = 0; i < (D * D / 4) / THREADS; ++i)
            wl[threadIdx.x + i * THREADS] = w4[threadIdx.x + i * THREADS];
    }
    __syncthreads();

    const int wave = threadIdx.x >> 6;
    const int lane = threadIdx.x & 63;
    const int half = lane >> 5;               // 0/1
    const int c4   = lane & 31;               // float4 column index

    const int  lA = wave * NPW + half;        // local node index (0..31)
    const int  lB = lA + 2;
    const long nA = (long)blockIdx.x * NPB + lA;
    const long nB = nA + 2;
    const bool vA = nA < n_nodes;
    const bool vB = nB < n_nodes;             // vB implies vA

    const f32x4* s4 = reinterpret_cast<const f32x4*>(self_vecs);
    const f32x4* g4 = reinterpret_cast<const f32x4*>(neigh_vecs);

    // ---- phase 1: aggregate self + 32 neighbours for 2 nodes ----
    constexpr float inv = 1.0f / (NEIGH + 1);
    f32x4 aA = (f32x4)0.0f;
    f32x4 aB = (f32x4)0.0f;

    if (vB) {
        aA = s4[nA * (D / 4) + c4];
        aB = s4[nB * (D / 4) + c4];
        const f32x4* pA = g4 + nA * (long)NEIGH * (D / 4) + c4;
        const f32x4* pB = g4 + nB * (long)NEIGH * (D / 4) + c4;
        #pragma unroll 8
        for (int r = 0; r < NEIGH; ++r) {
            f32x4 u = __builtin_nontemporal_load(&pA[(long)r * (D / 4)]);
            f32x4 v = __builtin_nontemporal_load(&pB[(long)r * (D / 4)]);
            aA += u;
            aB += v;
        }
    } else if (vA) {
        aA = s4[nA * (D / 4) + c4];
        const f32x4* pA = g4 + nA * (long)NEIGH * (D / 4) + c4;
        #pragma unroll 8
        for (int r = 0; r < NEIGH; ++r) {
            f32x4 u = __builtin_nontemporal_load(&pA[(long)r * (D / 4)]);
            aA += u;
        }
    }
    if (vA) reinterpret_cast<f32x4*>(agg_lds[lA])[c4] = aA * inv;
    if (vB) reinterpret_cast<f32x4*>(agg_lds[lB])[c4] = aB * inv;
    // no __syncthreads: rows lA/lB are produced and consumed by this wave only

    // ---- phase 2: out[n] = agg[n] @ W + bias, 2 nodes per lane ----
    f32x4 oA = (f32x4)0.0f;
    f32x4 oB = (f32x4)0.0f;
    const f32x4* wl  = reinterpret_cast<const f32x4*>(w_lds);
    const f32x4* arA = reinterpret_cast<const f32x4*>(agg_lds[lA]);
    const f32x4* arB = reinterpret_cast<const f32x4*>(agg_lds[lB]);
    #pragma unroll 4
    for (int k4 = 0; k4 < D / 4; ++k4) {
        f32x4 a0 = arA[k4];                          // broadcast within half
        f32x4 a1 = arB[k4];
        f32x4 w0 = wl[(4*k4 + 0) * (D/4) + c4];      // broadcast across halves
        f32x4 w1 = wl[(4*k4 + 1) * (D/4) + c4];
        f32x4 w2 = wl[(4*k4 + 2) * (D/4) + c4];
        f32x4 w3 = wl[(4*k4 + 3) * (D/4) + c4];
        oA += a0.x * w0;  oA += a0.y * w1;  oA += a0.z * w2;  oA += a0.w * w3;
        oB += a1.x * w0;  oB += a1.y * w1;  oB += a1.z * w2;  oB += a1.w * w3;
    }
    const f32x4 b = reinterpret_cast<const f32x4*>(bias)[c4];
    if (vA) reinterpret_cast<f32x4*>(out)[nA * (D / 4) + c4] = oA + b;
    if (vB) reinterpret_cast<f32x4*>(out)[nB * (D / 4) + c4] = oB + b;
}

extern "C" void kernel_launch(void* const* d_in, const int* in_sizes, int n_in,
                              void* d_out, int out_size, void* d_ws, size_t ws_size,
                              hipStream_t stream) {
    const float* self_vecs  = (const float*)d_in[0];
    const float* neigh_vecs = (const float*)d_in[1];
    // d_in[2] = neigh_num (==32, compile-time NEIGH)
    const float* weight     = (const float*)d_in[3];
    const float* bias       = (const float*)d_in[4];
    float*       out        = (float*)d_out;

    const int n_nodes = in_sizes[0] / D;                  // 50000
    const int blocks  = (n_nodes + NPB - 1) / NPB;        // 1563
    hipLaunchKernelGGL(sparse_layer_fused, dim3(blocks), dim3(THREADS), 0, stream,
                       self_vecs, neigh_vecs, weight, bias, out, n_nodes);
}